// Round 13
// baseline (66.835 us; speedup 1.0000x reference)
//
#include <hip/hip_runtime.h>
#include <math.h>

#define L2PI4      7.3515082656373812f   // 4*log(2*pi)
#define HALF_L2PI4 3.6757541328186906f   // 2*log(2*pi)
#define LOG2E      1.4426950408889634f
#define LN2        0.6931471805599453f
#define C_HQ       0.7213475204444817f   // 0.5*log2(e)

__device__ __forceinline__ float frcp(float x)  { return __builtin_amdgcn_rcpf(x); }
__device__ __forceinline__ float frsq(float x)  { return __builtin_amdgcn_rsqf(x); }
__device__ __forceinline__ float flog2(float x) { return __builtin_amdgcn_logf(x); }
__device__ __forceinline__ float fexp2(float x) { return __builtin_amdgcn_exp2f(x); }

// ---------------------------------------------------------------------------
// kL1: lr for the 128 leaf children (K=4, mixture = state directly).
// Side-band: blocks 0..23 precompute exp(2*var) tables for trans_p/lc/rc;
// block 0 zeroes the fin counter (stream-ordered before its use; replay-safe).
// lr[cn*500 + t4], t4 = ((lp*5+llc)*5+lrc)*4+c, natural-log domain.
// ---------------------------------------------------------------------------
__global__ __launch_bounds__(256) void kL1(
    const float* __restrict__ sw, const float* __restrict__ smu,
    const float* __restrict__ svar,
    const float4* __restrict__ tmL4, const float4* __restrict__ tvL4,
    const float4* __restrict__ tmR4, const float4* __restrict__ tvR4,
    const float* __restrict__ tvarp, const float* __restrict__ tvarl,
    const float* __restrict__ tvarr,
    float* __restrict__ tveP, float* __restrict__ tveL, float* __restrict__ tveR,
    float* __restrict__ lr, unsigned* __restrict__ cnt)
{
    int cn = blockIdx.x, side = cn & 1, tid = threadIdx.x;
    if (cn == 0 && tid == 0) *cnt = 0u;
    if (cn < 24) {
        int t = cn >> 3;                 // 0:P 1:L 2:R
        int base = (cn & 7) * 250;
        const float* src = (t == 0) ? tvarp : (t == 1) ? tvarl : tvarr;
        float* dst       = (t == 0) ? tveP  : (t == 1) ? tveL  : tveR;
        for (int i = tid; i < 250; i += 256)
            dst[base + i] = __expf(2.f * src[base + i]);
    }
    __shared__ float s_cm[80], s_cve[80], s_cw2[20];
    if (tid < 80) {
        s_cm[tid]  = smu[cn * 80 + tid];
        s_cve[tid] = __expf(2.f * svar[cn * 80 + tid]);
        if (tid < 20) s_cw2[tid] = (sw[cn * 20 + tid] - HALF_L2PI4) * LOG2E;
    }
    __syncthreads();
    const float4* tm = side ? tmR4 : tmL4;
    const float4* tv = side ? tvR4 : tvL4;
    for (int e = tid; e < 500; e += 256) {
        int c = e & 3, r = e >> 2;
        int lo = r % 5, r2 = r / 5, lp = r2 % 5, lc2 = r2 / 5;
        int idx = side ? (((lp * 5 + lo) * 5 + lc2) * 4 + c)
                       : (((lp * 5 + lc2) * 5 + lo) * 4 + c);
        float4 tmo = tm[idx];
        float4 tvr = tv[idx];
        float4 tvo = make_float4(__expf(2.f * tvr.x), __expf(2.f * tvr.y),
                                 __expf(2.f * tvr.z), __expf(2.f * tvr.w));
        float vals[4];
        #pragma unroll
        for (int k = 0; k < 4; ++k) {
            int ci = (lc2 * 4 + k) * 4;
            float s0 = s_cve[ci+0] + tvo.x, s1 = s_cve[ci+1] + tvo.y;
            float s2 = s_cve[ci+2] + tvo.z, s3 = s_cve[ci+3] + tvo.w;
            float d0 = s_cm[ci+0] - tmo.x, d1 = s_cm[ci+1] - tmo.y;
            float d2 = s_cm[ci+2] - tmo.z, d3 = s_cm[ci+3] - tmo.w;
            float p01 = s0 * s1, p23 = s2 * s3;
            float q01 = fmaf(d0 * d0, s1, d1 * d1 * s0);
            float q23 = fmaf(d2 * d2, s3, d3 * d3 * s2);
            float P = p01 * p23;
            float Q = fmaf(q01, p23, q23 * p01);
            float rq = frsq(P);
            float QP = Q * rq * rq;
            vals[k] = fmaf(-0.5f, flog2(P), fmaf(-C_HQ, QP, s_cw2[lc2 * 4 + k]));
        }
        float M = fmaxf(fmaxf(vals[0], vals[1]), fmaxf(vals[2], vals[3]));
        float S = fexp2(vals[0]-M) + fexp2(vals[1]-M)
                + fexp2(vals[2]-M) + fexp2(vals[3]-M);
        lr[(size_t)cn * 500 + idx] = (M + flog2(S)) * LN2;
    }
}

// ---------------------------------------------------------------------------
// kAB: one launch per parent-level m. block = (p, side, lc, lp), grid 50*m.
// Stage: rebuild child cn's 400-comp mixture into LDS (once per block).
// LSE:   i-outer — slot (fm,fv) loaded from LDS once, accumulated into
//        S[0..4]; tm/tv rows are wave-uniform LDS broadcasts. Live ~50 VGPR.
// doFin (final level, grid 50): last-arriver block computes the root
//        mixture -> d_out (50-arrival fetch_add, hang-free; r4/r10-proven).
// ---------------------------------------------------------------------------
__global__ __launch_bounds__(256) void kAB(
    const float* __restrict__ lrP, float* __restrict__ lrC,
    const float* __restrict__ sw, const float* __restrict__ smu,
    const float* __restrict__ svar, int childOff,
    const float* __restrict__ tw, const float4* __restrict__ tmp4,
    const float4* __restrict__ tep4,
    const float4* __restrict__ tmL4, const float4* __restrict__ tveL4,
    const float4* __restrict__ tmR4, const float4* __restrict__ tveR4,
    int log2m, int doFin, const float4* __restrict__ tvp4,
    unsigned* __restrict__ cnt, float* __restrict__ out)
{
    int bid = blockIdx.x;
    int p = bid & ((1 << log2m) - 1), sl = bid >> log2m;
    int side = (sl >= 25) ? 1 : 0;
    int r0 = sl - side * 25;
    int lc = r0 / 5, lp = r0 - lc * 5;
    int tid = threadIdx.x, lane = tid & 63, wave = tid >> 6;
    int cn = 2 * p + side;
    int node = childOff + cn;

    __shared__ float  s_sm[16], s_sve[16], s_swl[4];
    __shared__ float4 s_fm[400], s_fv[400];
    __shared__ float  s_fw[400];
    __shared__ float4 s_tm[20], s_tv[20];
    __shared__ int    s_idx[20];
    __shared__ int    s_last;

    if (tid < 16) {
        s_sm[tid]  = smu[node * 80 + lc * 16 + tid];
        s_sve[tid] = __expf(2.f * svar[node * 80 + lc * 16 + tid]);
        if (tid < 4) s_swl[tid] = sw[node * 20 + lc * 4 + tid];
    }
    {   // stage 20 output trans rows (wave-uniform reads later -> broadcast)
        const float4* tmf  = side ? tmR4  : tmL4;
        const float4* tvef = side ? tveR4 : tveL4;
        if (tid >= 64 && tid < 84) {
            int o = tid - 64, lo = o >> 2, c = o & 3;
            int idx = side ? (((lp * 5 + lo) * 5 + lc) * 4 + c)
                           : (((lp * 5 + lc) * 5 + lo) * 4 + c);
            s_idx[o] = idx;
            s_tm[o]  = tmf[idx];
            s_tv[o]  = tvef[idx];
        }
    }
    __syncthreads();

    const float* lrL = lrP + (size_t)(2 * cn) * 500;
    const float* lrR = lrP + (size_t)(2 * cn + 1) * 500;

    // ---- Stage: rebuild child mixture into LDS (1.6 comps/thread) --------
    for (int e = tid; e < 400; e += 256) {
        int c2 = e & 3, ks = (e >> 2) & 3, r = e >> 4;
        int t4 = (lc * 25 + r) * 4 + c2;
        float csv = lrL[t4] + lrR[t4] + tw[t4];
        float4 m2 = tmp4[t4], e2 = tep4[t4];
        float base2 = (csv + s_swl[ks] - L2PI4) * LOG2E;
        float v0 = s_sve[ks*4+0], v1 = s_sve[ks*4+1];
        float v2 = s_sve[ks*4+2], v3 = s_sve[ks*4+3];
        float m10 = s_sm[ks*4+0], m11 = s_sm[ks*4+1];
        float m12 = s_sm[ks*4+2], m13 = s_sm[ks*4+3];
        float s0 = v0 + e2.x, s1 = v1 + e2.y, s2 = v2 + e2.z, s3 = v3 + e2.w;
        float rs0 = frcp(s0), rs1 = frcp(s1), rs2 = frcp(s2), rs3 = frcp(s3);
        float d0 = m10 - m2.x, d1 = m11 - m2.y, d2 = m12 - m2.z, d3 = m13 - m2.w;
        float qs = fmaf(d0 * d0, rs0, fmaf(d1 * d1, rs1,
                   fmaf(d2 * d2, rs2, d3 * d3 * rs3)));
        float P = (s0 * s1) * (s2 * s3);
        float4 fm, fv;
        fm.x = fmaf(m10, e2.x, m2.x * v0) * rs0;  fv.x = v0 * e2.x * rs0;
        fm.y = fmaf(m11, e2.y, m2.y * v1) * rs1;  fv.y = v1 * e2.y * rs1;
        fm.z = fmaf(m12, e2.z, m2.z * v2) * rs2;  fv.z = v2 * e2.z * rs2;
        fm.w = fmaf(m13, e2.w, m2.w * v3) * rs3;  fv.w = v3 * e2.w * rs3;
        s_fm[e] = fm;
        s_fv[e] = fv;
        s_fw[e] = fmaf(-0.5f, flog2(P), fmaf(-C_HQ, qs, base2));
    }
    __syncthreads();

    // ---- E[i] = exp2(fw - M), M = max over all 400 (block-uniform) -------
    float E[7], M;
    {
        float w[7];
        #pragma unroll
        for (int i = 0; i < 7; ++i) {
            int k = lane + (i << 6);
            w[i] = (k < 400) ? s_fw[k] : -1e30f;
        }
        M = w[0];
        #pragma unroll
        for (int i = 1; i < 7; ++i) M = fmaxf(M, w[i]);
        #pragma unroll
        for (int s = 32; s; s >>= 1) M = fmaxf(M, __shfl_xor(M, s));
        #pragma unroll
        for (int i = 0; i < 7; ++i) E[i] = fexp2(w[i] - M);   // padded -> 0
    }

    // ---- LSE: i-outer; slot in regs, tm/tv as uniform LDS broadcast ------
    float S[5] = {0.f, 0.f, 0.f, 0.f, 0.f};
    #pragma unroll
    for (int i = 0; i < 7; ++i) {
        int k = lane + (i << 6);
        int kc = k < 400 ? k : 0;
        float4 fm = s_fm[kc], fv = s_fv[kc];
        float Ei = E[i];                  // 0 for padded slots
        #pragma unroll
        for (int j = 0; j < 5; ++j) {
            int o = wave + 4 * j;
            float4 tmo = s_tm[o], tvo = s_tv[o];
            float ss0 = fv.x + tvo.x, ss1 = fv.y + tvo.y;
            float ss2 = fv.z + tvo.z, ss3 = fv.w + tvo.w;
            float dd0 = fm.x - tmo.x, dd1 = fm.y - tmo.y;
            float dd2 = fm.z - tmo.z, dd3 = fm.w - tmo.w;
            float p01 = ss0 * ss1, p23 = ss2 * ss3;
            float q01 = fmaf(dd0 * dd0, ss1, dd1 * dd1 * ss0);
            float q23 = fmaf(dd2 * dd2, ss3, dd3 * dd3 * ss2);
            float P = p01 * p23;
            float Q = fmaf(q01, p23, q23 * p01);
            float rq = frsq(P);
            float QP = Q * rq * rq;
            S[j] = fmaf(Ei * rq, fexp2(-C_HQ * QP), S[j]);
        }
    }
    #pragma unroll
    for (int s = 32; s; s >>= 1) {
        #pragma unroll
        for (int j = 0; j < 5; ++j) S[j] += __shfl_xor(S[j], s);
    }
    if (lane == 0) {
        size_t lrb = (size_t)cn * 500;
        #pragma unroll
        for (int j = 0; j < 5; ++j)
            lrC[lrb + s_idx[wave + 4 * j]] = (M + flog2(S[j])) * LN2;
    }

    // ---- fused fin (final level only): last-arriver does root mixture ----
    if (!doFin) return;
    __syncthreads();
    if (tid == 0) {
        __builtin_amdgcn_fence(__ATOMIC_RELEASE, "agent");
        unsigned old = __hip_atomic_fetch_add(cnt, 1u, __ATOMIC_RELAXED,
                                              __HIP_MEMORY_SCOPE_AGENT);
        s_last = (old == 49u);
    }
    __syncthreads();
    if (!s_last) return;
    __builtin_amdgcn_fence(__ATOMIC_ACQUIRE, "agent");

    float4* outmu4  = (float4*)(out + 2000);
    float4* outvar4 = (float4*)(out + 10000);
    for (int e = tid; e < 2000; e += 256) {
        int c = e & 3, ks = (e >> 2) & 3, r = e >> 4;
        int lrc = r % 5, r2 = r / 5, llc = r2 % 5, lp2 = r2 / 5;
        int t4 = ((lp2 * 5 + llc) * 5 + lrc) * 4 + c;
        float csv = lrC[t4] + lrC[500 + t4] + tw[t4];
        float4 m2 = tmp4[t4], v2 = tvp4[t4], e2 = tep4[t4];
        int sb = 254 * 80 + (lp2 * 4 + ks) * 4;
        float base = csv + sw[254 * 20 + lp2 * 4 + ks] - HALF_L2PI4;
        float scale = 0.f;
        float4 pmu, pvar;
        {
            float m1 = smu[sb+0], v1 = svar[sb+0], v1s = __expf(2.f * v1);
            float s = v1s + e2.x, rs = frcp(s), ls = flog2(s) * LN2, df = m1 - m2.x;
            scale += ls + df * df * rs;
            pmu.x = fmaf(m1, e2.x, m2.x * v1s) * rs; pvar.x = v1 + v2.x - 0.5f * ls;
        }
        {
            float m1 = smu[sb+1], v1 = svar[sb+1], v1s = __expf(2.f * v1);
            float s = v1s + e2.y, rs = frcp(s), ls = flog2(s) * LN2, df = m1 - m2.y;
            scale += ls + df * df * rs;
            pmu.y = fmaf(m1, e2.y, m2.y * v1s) * rs; pvar.y = v1 + v2.y - 0.5f * ls;
        }
        {
            float m1 = smu[sb+2], v1 = svar[sb+2], v1s = __expf(2.f * v1);
            float s = v1s + e2.z, rs = frcp(s), ls = flog2(s) * LN2, df = m1 - m2.z;
            scale += ls + df * df * rs;
            pmu.z = fmaf(m1, e2.z, m2.z * v1s) * rs; pvar.z = v1 + v2.z - 0.5f * ls;
        }
        {
            float m1 = smu[sb+3], v1 = svar[sb+3], v1s = __expf(2.f * v1);
            float s = v1s + e2.w, rs = frcp(s), ls = flog2(s) * LN2, df = m1 - m2.w;
            scale += ls + df * df * rs;
            pmu.w = fmaf(m1, e2.w, m2.w * v1s) * rs; pvar.w = v1 + v2.w - 0.5f * ls;
        }
        out[e]     = fmaf(-0.5f, scale, base);
        outmu4[e]  = pmu;
        outvar4[e] = pvar;
    }
}

// ---------------------------------------------------------------------------
// Launcher: 7 launches, no memset. ws layout (floats):
//   lrA[64000] lrB[64000] tveP[2000] tveL[2000] tveR[2000] cnt[1 u32]
// ---------------------------------------------------------------------------
extern "C" void kernel_launch(void* const* d_in, const int* in_sizes, int n_in,
                              void* d_out, int out_size, void* d_ws, size_t ws_size,
                              hipStream_t stream) {
    (void)in_sizes; (void)n_in; (void)out_size; (void)ws_size;
    const float* sw      = (const float*)d_in[0];
    const float* smu     = (const float*)d_in[1];
    const float* svar    = (const float*)d_in[2];
    const float* tw      = (const float*)d_in[3];
    const float* tmu_p   = (const float*)d_in[4];
    const float* tmu_lc  = (const float*)d_in[5];
    const float* tmu_rc  = (const float*)d_in[6];
    const float* tvar_p  = (const float*)d_in[7];
    const float* tvar_lc = (const float*)d_in[8];
    const float* tvar_rc = (const float*)d_in[9];

    float* ws   = (float*)d_ws;
    float* lrA  = ws;
    float* lrB  = lrA + 64000;
    float* tveP = lrB + 64000;
    float* tveL = tveP + 2000;
    float* tveR = tveL + 2000;
    unsigned* cnt = (unsigned*)(tveR + 2000);
    float* out  = (float*)d_out;

    hipLaunchKernelGGL(kL1, dim3(128), dim3(256), 0, stream,
                       sw, smu, svar,
                       (const float4*)tmu_lc, (const float4*)tvar_lc,
                       (const float4*)tmu_rc, (const float4*)tvar_rc,
                       tvar_p, tvar_lc, tvar_rc,
                       tveP, tveL, tveR, lrA, cnt);

    // (m, childOff): children of level-m parents live at childOff..childOff+2m-1
    const int childOffs[6] = {128, 192, 224, 240, 248, 252};
    float* lrP = lrA;
    float* lrC = lrB;
    int li = 0;
    for (int lg = 5; lg >= 0; --lg, ++li) {
        int m = 1 << lg;
        int fin = (m == 1);
        hipLaunchKernelGGL(kAB, dim3(50 * m), dim3(256), 0, stream,
                           lrP, lrC,
                           sw, smu, svar, childOffs[li],
                           tw, (const float4*)tmu_p, (const float4*)tveP,
                           (const float4*)tmu_lc, (const float4*)tveL,
                           (const float4*)tmu_rc, (const float4*)tveR,
                           lg, fin, (const float4*)tvar_p, cnt, out);
        float* t = lrP; lrP = lrC; lrC = t;
    }
}

// Round 14
// 63.064 us; speedup vs baseline: 1.0598x; 1.0598x over previous
//
#include <hip/hip_runtime.h>
#include <math.h>

#define L2PI4      7.3515082656373812f   // 4*log(2*pi)
#define HALF_L2PI4 3.6757541328186906f   // 2*log(2*pi)
#define LOG2E      1.4426950408889634f
#define LN2        0.6931471805599453f
#define C_HQ       0.7213475204444817f   // 0.5*log2(e)

__device__ __forceinline__ float frcp(float x)  { return __builtin_amdgcn_rcpf(x); }
__device__ __forceinline__ float frsq(float x)  { return __builtin_amdgcn_rsqf(x); }
__device__ __forceinline__ float flog2(float x) { return __builtin_amdgcn_logf(x); }
__device__ __forceinline__ float fexp2(float x) { return __builtin_amdgcn_exp2f(x); }

// ---------------------------------------------------------------------------
// kL1: lr for the 128 leaf children (K=4, mixture = state directly).
// Side-band: blocks 0..23 precompute exp(2*var) tables for trans_p/lc/rc.
// lr[cn*500 + t4], t4 = ((lp*5+llc)*5+lrc)*4+c, natural-log domain.
// ---------------------------------------------------------------------------
__global__ __launch_bounds__(256) void kL1(
    const float* __restrict__ sw, const float* __restrict__ smu,
    const float* __restrict__ svar,
    const float4* __restrict__ tmL4, const float4* __restrict__ tvL4,
    const float4* __restrict__ tmR4, const float4* __restrict__ tvR4,
    const float* __restrict__ tvarp, const float* __restrict__ tvarl,
    const float* __restrict__ tvarr,
    float* __restrict__ tveP, float* __restrict__ tveL, float* __restrict__ tveR,
    float* __restrict__ lr)
{
    int cn = blockIdx.x, side = cn & 1, tid = threadIdx.x;
    if (cn < 24) {
        int t = cn >> 3;                 // 0:P 1:L 2:R
        int base = (cn & 7) * 250;
        const float* src = (t == 0) ? tvarp : (t == 1) ? tvarl : tvarr;
        float* dst       = (t == 0) ? tveP  : (t == 1) ? tveL  : tveR;
        for (int i = tid; i < 250; i += 256)
            dst[base + i] = __expf(2.f * src[base + i]);
    }
    __shared__ float s_cm[80], s_cve[80], s_cw2[20];
    if (tid < 80) {
        s_cm[tid]  = smu[cn * 80 + tid];
        s_cve[tid] = __expf(2.f * svar[cn * 80 + tid]);
        if (tid < 20) s_cw2[tid] = (sw[cn * 20 + tid] - HALF_L2PI4) * LOG2E;
    }
    __syncthreads();
    const float4* tm = side ? tmR4 : tmL4;
    const float4* tv = side ? tvR4 : tvL4;
    for (int e = tid; e < 500; e += 256) {
        int c = e & 3, r = e >> 2;
        int lo = r % 5, r2 = r / 5, lp = r2 % 5, lc2 = r2 / 5;
        int idx = side ? (((lp * 5 + lo) * 5 + lc2) * 4 + c)
                       : (((lp * 5 + lc2) * 5 + lo) * 4 + c);
        float4 tmo = tm[idx];
        float4 tvr = tv[idx];
        float4 tvo = make_float4(__expf(2.f * tvr.x), __expf(2.f * tvr.y),
                                 __expf(2.f * tvr.z), __expf(2.f * tvr.w));
        float vals[4];
        #pragma unroll
        for (int k = 0; k < 4; ++k) {
            int ci = (lc2 * 4 + k) * 4;
            float s0 = s_cve[ci+0] + tvo.x, s1 = s_cve[ci+1] + tvo.y;
            float s2 = s_cve[ci+2] + tvo.z, s3 = s_cve[ci+3] + tvo.w;
            float d0 = s_cm[ci+0] - tmo.x, d1 = s_cm[ci+1] - tmo.y;
            float d2 = s_cm[ci+2] - tmo.z, d3 = s_cm[ci+3] - tmo.w;
            float p01 = s0 * s1, p23 = s2 * s3;
            float q01 = fmaf(d0 * d0, s1, d1 * d1 * s0);
            float q23 = fmaf(d2 * d2, s3, d3 * d3 * s2);
            float P = p01 * p23;
            float Q = fmaf(q01, p23, q23 * p01);
            float rq = frsq(P);
            float QP = Q * rq * rq;
            vals[k] = fmaf(-0.5f, flog2(P), fmaf(-C_HQ, QP, s_cw2[lc2 * 4 + k]));
        }
        float M = fmaxf(fmaxf(vals[0], vals[1]), fmaxf(vals[2], vals[3]));
        float S = fexp2(vals[0]-M) + fexp2(vals[1]-M)
                + fexp2(vals[2]-M) + fexp2(vals[3]-M);
        lr[(size_t)cn * 500 + idx] = (M + flog2(S)) * LN2;
    }
}

// ---------------------------------------------------------------------------
// kAB: one launch per parent-level m. block = (p, side, lc, lp), grid 50*m.
// Stage: rebuild child cn's 400-comp mixture into LDS (once per block).
// LSE:   i-OUTER — each lane loads its slot (fm,fv) from LDS ONCE and
//        accumulates into S[0..4]; tm/tv rows read as wave-uniform LDS
//        broadcasts. Live set ~50 VGPR (< 64 by construction).
// ---------------------------------------------------------------------------
__global__ __launch_bounds__(256) void kAB(
    const float* __restrict__ lrP, float* __restrict__ lrC,
    const float* __restrict__ sw, const float* __restrict__ smu,
    const float* __restrict__ svar, int childOff,
    const float* __restrict__ tw, const float4* __restrict__ tmp4,
    const float4* __restrict__ tep4,
    const float4* __restrict__ tmL4, const float4* __restrict__ tveL4,
    const float4* __restrict__ tmR4, const float4* __restrict__ tveR4,
    int log2m)
{
    int bid = blockIdx.x;
    int p = bid & ((1 << log2m) - 1), sl = bid >> log2m;
    int side = (sl >= 25) ? 1 : 0;
    int r0 = sl - side * 25;
    int lc = r0 / 5, lp = r0 - lc * 5;
    int tid = threadIdx.x, lane = tid & 63, wave = tid >> 6;
    int cn = 2 * p + side;
    int node = childOff + cn;

    __shared__ float  s_sm[16], s_sve[16], s_swl[4];
    __shared__ float4 s_fm[400], s_fv[400];
    __shared__ float  s_fw[400];
    __shared__ float4 s_tm[20], s_tv[20];
    __shared__ int    s_idx[20];

    if (tid < 16) {
        s_sm[tid]  = smu[node * 80 + lc * 16 + tid];
        s_sve[tid] = __expf(2.f * svar[node * 80 + lc * 16 + tid]);
        if (tid < 4) s_swl[tid] = sw[node * 20 + lc * 4 + tid];
    }
    {   // stage 20 output trans rows (wave-uniform reads later -> broadcast)
        const float4* tmf  = side ? tmR4  : tmL4;
        const float4* tvef = side ? tveR4 : tveL4;
        if (tid >= 64 && tid < 84) {
            int o = tid - 64, lo = o >> 2, c = o & 3;
            int idx = side ? (((lp * 5 + lo) * 5 + lc) * 4 + c)
                           : (((lp * 5 + lc) * 5 + lo) * 4 + c);
            s_idx[o] = idx;
            s_tm[o]  = tmf[idx];
            s_tv[o]  = tvef[idx];
        }
    }
    __syncthreads();

    const float* lrL = lrP + (size_t)(2 * cn) * 500;
    const float* lrR = lrP + (size_t)(2 * cn + 1) * 500;

    // ---- Stage: rebuild child mixture into LDS (1.6 comps/thread) --------
    for (int e = tid; e < 400; e += 256) {
        int c2 = e & 3, ks = (e >> 2) & 3, r = e >> 4;
        int t4 = (lc * 25 + r) * 4 + c2;
        float csv = lrL[t4] + lrR[t4] + tw[t4];
        float4 m2 = tmp4[t4], e2 = tep4[t4];
        float base2 = (csv + s_swl[ks] - L2PI4) * LOG2E;
        float v0 = s_sve[ks*4+0], v1 = s_sve[ks*4+1];
        float v2 = s_sve[ks*4+2], v3 = s_sve[ks*4+3];
        float m10 = s_sm[ks*4+0], m11 = s_sm[ks*4+1];
        float m12 = s_sm[ks*4+2], m13 = s_sm[ks*4+3];
        float s0 = v0 + e2.x, s1 = v1 + e2.y, s2 = v2 + e2.z, s3 = v3 + e2.w;
        float rs0 = frcp(s0), rs1 = frcp(s1), rs2 = frcp(s2), rs3 = frcp(s3);
        float d0 = m10 - m2.x, d1 = m11 - m2.y, d2 = m12 - m2.z, d3 = m13 - m2.w;
        float qs = fmaf(d0 * d0, rs0, fmaf(d1 * d1, rs1,
                   fmaf(d2 * d2, rs2, d3 * d3 * rs3)));
        float P = (s0 * s1) * (s2 * s3);
        float4 fm, fv;
        fm.x = fmaf(m10, e2.x, m2.x * v0) * rs0;  fv.x = v0 * e2.x * rs0;
        fm.y = fmaf(m11, e2.y, m2.y * v1) * rs1;  fv.y = v1 * e2.y * rs1;
        fm.z = fmaf(m12, e2.z, m2.z * v2) * rs2;  fv.z = v2 * e2.z * rs2;
        fm.w = fmaf(m13, e2.w, m2.w * v3) * rs3;  fv.w = v3 * e2.w * rs3;
        s_fm[e] = fm;
        s_fv[e] = fv;
        s_fw[e] = fmaf(-0.5f, flog2(P), fmaf(-C_HQ, qs, base2));
    }
    __syncthreads();

    // ---- E[i] = exp2(fw - M), M = max over all 400 (block-uniform) -------
    float E[7], M;
    {
        float w[7];
        #pragma unroll
        for (int i = 0; i < 7; ++i) {
            int k = lane + (i << 6);
            w[i] = (k < 400) ? s_fw[k] : -1e30f;
        }
        M = w[0];
        #pragma unroll
        for (int i = 1; i < 7; ++i) M = fmaxf(M, w[i]);
        #pragma unroll
        for (int s = 32; s; s >>= 1) M = fmaxf(M, __shfl_xor(M, s));
        #pragma unroll
        for (int i = 0; i < 7; ++i) E[i] = fexp2(w[i] - M);   // padded -> 0
    }

    // ---- LSE: i-outer; slot in regs, tm/tv as uniform LDS broadcast ------
    float S[5] = {0.f, 0.f, 0.f, 0.f, 0.f};
    #pragma unroll
    for (int i = 0; i < 7; ++i) {
        int k = lane + (i << 6);
        int kc = k < 400 ? k : 0;
        float4 fm = s_fm[kc], fv = s_fv[kc];
        float Ei = E[i];                  // 0 for padded slots
        #pragma unroll
        for (int j = 0; j < 5; ++j) {
            int o = wave + 4 * j;
            float4 tmo = s_tm[o], tvo = s_tv[o];
            float ss0 = fv.x + tvo.x, ss1 = fv.y + tvo.y;
            float ss2 = fv.z + tvo.z, ss3 = fv.w + tvo.w;
            float dd0 = fm.x - tmo.x, dd1 = fm.y - tmo.y;
            float dd2 = fm.z - tmo.z, dd3 = fm.w - tmo.w;
            float p01 = ss0 * ss1, p23 = ss2 * ss3;
            float q01 = fmaf(dd0 * dd0, ss1, dd1 * dd1 * ss0);
            float q23 = fmaf(dd2 * dd2, ss3, dd3 * dd3 * ss2);
            float P = p01 * p23;
            float Q = fmaf(q01, p23, q23 * p01);
            float rq = frsq(P);
            float QP = Q * rq * rq;
            S[j] = fmaf(Ei * rq, fexp2(-C_HQ * QP), S[j]);
        }
    }
    #pragma unroll
    for (int s = 32; s; s >>= 1) {
        #pragma unroll
        for (int j = 0; j < 5; ++j) S[j] += __shfl_xor(S[j], s);
    }
    if (lane == 0) {
        size_t lrb = (size_t)cn * 500;
        #pragma unroll
        for (int j = 0; j < 5; ++j)
            lrC[lrb + s_idx[wave + 4 * j]] = (M + flog2(S[j])) * LN2;
    }
}

// ---------------------------------------------------------------------------
// kFin: root mixture (w, mu, var) -> d_out. 2000 outputs, one per thread.
// ---------------------------------------------------------------------------
__global__ __launch_bounds__(256) void kFin(
    const float* __restrict__ lrC,
    const float* __restrict__ sw, const float* __restrict__ smu,
    const float* __restrict__ svar, int rootNode,
    const float* __restrict__ tw, const float4* __restrict__ tmp4,
    const float4* __restrict__ tvp4, const float4* __restrict__ tep4,
    float* __restrict__ outw, float4* __restrict__ outmu4,
    float4* __restrict__ outvar4)
{
    int e = blockIdx.x * 256 + threadIdx.x;
    if (e >= 2000) return;
    int c = e & 3, ks = (e >> 2) & 3, r = e >> 4;
    int lrc = r % 5, r2 = r / 5, llc = r2 % 5, lp = r2 / 5;
    int t4 = ((lp * 5 + llc) * 5 + lrc) * 4 + c;
    float csv = lrC[t4] + lrC[500 + t4] + tw[t4];
    float4 m2 = tmp4[t4], v2 = tvp4[t4], e2 = tep4[t4];
    int sb = rootNode * 80 + (lp * 4 + ks) * 4;
    float base = csv + sw[rootNode * 20 + lp * 4 + ks] - HALF_L2PI4;
    float scale = 0.f;
    float4 pmu, pvar;
    {
        float m1 = smu[sb+0], v1 = svar[sb+0], v1s = __expf(2.f * v1);
        float s = v1s + e2.x, rs = frcp(s), ls = flog2(s) * LN2, df = m1 - m2.x;
        scale += ls + df * df * rs;
        pmu.x = fmaf(m1, e2.x, m2.x * v1s) * rs; pvar.x = v1 + v2.x - 0.5f * ls;
    }
    {
        float m1 = smu[sb+1], v1 = svar[sb+1], v1s = __expf(2.f * v1);
        float s = v1s + e2.y, rs = frcp(s), ls = flog2(s) * LN2, df = m1 - m2.y;
        scale += ls + df * df * rs;
        pmu.y = fmaf(m1, e2.y, m2.y * v1s) * rs; pvar.y = v1 + v2.y - 0.5f * ls;
    }
    {
        float m1 = smu[sb+2], v1 = svar[sb+2], v1s = __expf(2.f * v1);
        float s = v1s + e2.z, rs = frcp(s), ls = flog2(s) * LN2, df = m1 - m2.z;
        scale += ls + df * df * rs;
        pmu.z = fmaf(m1, e2.z, m2.z * v1s) * rs; pvar.z = v1 + v2.z - 0.5f * ls;
    }
    {
        float m1 = smu[sb+3], v1 = svar[sb+3], v1s = __expf(2.f * v1);
        float s = v1s + e2.w, rs = frcp(s), ls = flog2(s) * LN2, df = m1 - m2.w;
        scale += ls + df * df * rs;
        pmu.w = fmaf(m1, e2.w, m2.w * v1s) * rs; pvar.w = v1 + v2.w - 0.5f * ls;
    }
    outw[e]    = fmaf(-0.5f, scale, base);
    outmu4[e]  = pmu;
    outvar4[e] = pvar;
}

// ---------------------------------------------------------------------------
// Launcher: 8 launches, no atomics. ws layout (floats):
//   lrA[64000] lrB[64000] tveP[2000] tveL[2000] tveR[2000]
// ---------------------------------------------------------------------------
extern "C" void kernel_launch(void* const* d_in, const int* in_sizes, int n_in,
                              void* d_out, int out_size, void* d_ws, size_t ws_size,
                              hipStream_t stream) {
    (void)in_sizes; (void)n_in; (void)out_size; (void)ws_size;
    const float* sw      = (const float*)d_in[0];
    const float* smu     = (const float*)d_in[1];
    const float* svar    = (const float*)d_in[2];
    const float* tw      = (const float*)d_in[3];
    const float* tmu_p   = (const float*)d_in[4];
    const float* tmu_lc  = (const float*)d_in[5];
    const float* tmu_rc  = (const float*)d_in[6];
    const float* tvar_p  = (const float*)d_in[7];
    const float* tvar_lc = (const float*)d_in[8];
    const float* tvar_rc = (const float*)d_in[9];

    float* ws   = (float*)d_ws;
    float* lrA  = ws;
    float* lrB  = lrA + 64000;
    float* tveP = lrB + 64000;
    float* tveL = tveP + 2000;
    float* tveR = tveL + 2000;
    float* out  = (float*)d_out;

    hipLaunchKernelGGL(kL1, dim3(128), dim3(256), 0, stream,
                       sw, smu, svar,
                       (const float4*)tmu_lc, (const float4*)tvar_lc,
                       (const float4*)tmu_rc, (const float4*)tvar_rc,
                       tvar_p, tvar_lc, tvar_rc,
                       tveP, tveL, tveR, lrA);

    // (m, childOff): children of level-m parents live at childOff..childOff+2m-1
    const int childOffs[6] = {128, 192, 224, 240, 248, 252};
    float* lrP = lrA;
    float* lrC = lrB;
    int li = 0;
    for (int lg = 5; lg >= 0; --lg, ++li) {
        int m = 1 << lg;
        hipLaunchKernelGGL(kAB, dim3(50 * m), dim3(256), 0, stream,
                           lrP, lrC,
                           sw, smu, svar, childOffs[li],
                           tw, (const float4*)tmu_p, (const float4*)tveP,
                           (const float4*)tmu_lc, (const float4*)tveL,
                           (const float4*)tmu_rc, (const float4*)tveR,
                           lg);
        float* t = lrP; lrP = lrC; lrC = t;
    }
    // after loop, last level's output is in lrP (entries 0,1)
    hipLaunchKernelGGL(kFin, dim3(8), dim3(256), 0, stream,
                       lrP, sw, smu, svar, 254,
                       tw, (const float4*)tmu_p, (const float4*)tvar_p,
                       (const float4*)tveP,
                       out, (float4*)(out + 2000), (float4*)(out + 10000));
}